// Round 2
// baseline (1305.866 us; speedup 1.0000x reference)
//
#include <hip/hip_runtime.h>

// WaveCell: 2D wave equation, B=4, T=300, 256x256, PML coeffs.
// Persistent cooperative kernel; row-stripe temporal blocking.
//   256 blocks = 4 batches x 64 stripes (R=4 core rows); 256 threads/block.
//   Thread layout: wave w = tid>>6 (4 waves), lane j = tid&63; thread owns
//   cols [4j,4j+4) of one row at a time (float4 / ds_read_b128 everywhere).
//   K=10 steps per grid barrier; LDS window NW=R+2K=24 rows x 2 frames (48KB).
//   Coefficients (P=A1*A2, Q=A1*A3, R=A1*c2/h^2) live in REGISTERS: wave w
//   owns fixed rows [1+6w, 1+6w+6) of the window (statically unrolled).
//   d_out doubles as state: halo rows reload from frames t0-1/t0-2 per round.
//   Per-step core-row stores issued right AFTER the step barrier so they
//   retire under the next step's compute (no vmcnt drain at s_barrier).
//   Per-batch grid barriers (4 groups of 64 blocks) in d_ws.

#define NXg 256
#define NYg 256
#define Bg  4
#define Tg  300
#define Kg  10
#define Rg  4
#define NWg (Rg + 2 * Kg)   // 24
#define STRIPES (NXg / Rg)  // 64
#define NBLK (Bg * STRIPES) // 256
#define GRP STRIPES         // blocks per batch barrier group
#define CHUNK 6             // ceil((NWg-2)/4) rows per wave

static_assert(Tg % Kg == 0, "T must be a multiple of K");
static_assert((Kg % 2) == 0, "even K keeps u1/u2 pointer parity per round");

__device__ __forceinline__ void batch_barrier(unsigned* cnt, unsigned* gen) {
  __syncthreads();
  if (threadIdx.x == 0) {
    __threadfence();  // release frame stores (vmcnt drain + L2 writeback)
    unsigned g = __hip_atomic_load(gen, __ATOMIC_RELAXED, __HIP_MEMORY_SCOPE_AGENT);
    unsigned a = __hip_atomic_fetch_add(cnt, 1u, __ATOMIC_ACQ_REL, __HIP_MEMORY_SCOPE_AGENT);
    if (a == GRP - 1u) {
      __hip_atomic_store(cnt, 0u, __ATOMIC_RELAXED, __HIP_MEMORY_SCOPE_AGENT);
      __hip_atomic_fetch_add(gen, 1u, __ATOMIC_RELEASE, __HIP_MEMORY_SCOPE_AGENT);
    } else {
      while (__hip_atomic_load(gen, __ATOMIC_ACQUIRE, __HIP_MEMORY_SCOPE_AGENT) == g)
        __builtin_amdgcn_s_sleep(1);
    }
  }
  __syncthreads();
}

__device__ __forceinline__ float4 ld4g(const float* p) {
  return *reinterpret_cast<const float4*>(p);
}
__device__ __forceinline__ void st4g(float* p, float4 v) {
  *reinterpret_cast<float4*>(p) = v;
}

__global__ __launch_bounds__(256, 1)
void WaveCell_14894946582958_kernel(const float* __restrict__ x,
                                    const float* __restrict__ c2,
                                    const float* __restrict__ A1,
                                    const float* __restrict__ A3,
                                    const float* __restrict__ A2p,
                                    const float* __restrict__ ih2p,
                                    const int*   __restrict__ sxp,
                                    const int*   __restrict__ syp,
                                    float* __restrict__ out,
                                    unsigned* __restrict__ bar) {
  __shared__ __align__(16) float Ua[NWg * NYg];  // frame buffer A
  __shared__ __align__(16) float Ub[NWg * NYg];  // frame buffer B
  __shared__ float xs[Tg];                       // this batch's source series

  const int tid = threadIdx.x;
  const int w   = __builtin_amdgcn_readfirstlane(tid >> 6);  // wave id 0..3
  const int j   = tid & 63;                                  // col group
  const int j4  = j << 2;
  const int bid = blockIdx.x;
  const int b      = bid >> 6;       // batch
  const int stripe = bid & 63;
  const int r0     = stripe << 2;    // first core row
  const int wbase  = r0 - Kg;        // global row of window row 0

  const float A2v = A2p[0];
  const float ih2 = ih2p[0];
  const int sx = sxp[0], sy = syp[0];

  // ---- coefficients for my fixed chunk rows, in registers ----
  const int start = 1 + w * CHUNK;   // 1, 7, 13, 19
  float4 Pc[CHUNK], Qc[CHUNK], Rc[CHUNK];
#pragma unroll
  for (int q = 0; q < CHUNK; ++q) {
    const int row = start + q;
    const int gr  = wbase + row;
    float4 a1 = {0.f, 0.f, 0.f, 0.f};
    float4 a3 = a1, cc = a1;
    if (row <= NWg - 2 && gr >= 0 && gr < NXg) {
      a1 = ld4g(A1 + gr * NYg + j4);
      a3 = ld4g(A3 + gr * NYg + j4);
      cc = ld4g(c2 + gr * NYg + j4);
    }
    Pc[q].x = a1.x * A2v; Pc[q].y = a1.y * A2v; Pc[q].z = a1.z * A2v; Pc[q].w = a1.w * A2v;
    Qc[q].x = a1.x * a3.x; Qc[q].y = a1.y * a3.y; Qc[q].z = a1.z * a3.z; Qc[q].w = a1.w * a3.w;
    Rc[q].x = a1.x * cc.x * ih2; Rc[q].y = a1.y * cc.y * ih2;
    Rc[q].z = a1.z * cc.z * ih2; Rc[q].w = a1.w * cc.w * ih2;
  }

  // ---- zero both frame buffers (frames -1, -2 = 0), load source series ----
  {
    const float4 z = {0.f, 0.f, 0.f, 0.f};
#pragma unroll
    for (int q = 0; q < CHUNK; ++q) {
      const int row = (q << 2) + w;  // covers 0..23
      st4g(Ua + row * NYg + j4, z);
      st4g(Ub + row * NYg + j4, z);
    }
    for (int i = tid; i < Tg; i += 256) xs[i] = x[b * Tg + i];
  }
  __syncthreads();

  float* u1 = Ua;  // frame t-1
  float* u2 = Ub;  // frame t-2 (overwritten in place with frame t)
  unsigned* cnt = bar + (b << 5);    // 128B apart per batch
  unsigned* gen = cnt + 1;

  const int si   = sx - wbase;       // source row in window coords
  const int jsrc = sy >> 2;
  const int wsrc = (si >= 1 && si <= NWg - 2) ? ((si - 1) / CHUNK) : -1;

  for (int t0 = 0; t0 < Tg; t0 += Kg) {
    if (t0) {
      batch_barrier(cnt, gen);
      // Reload halo rows of frames t0-1 -> u1, t0-2 -> u2 (core rows are
      // already current in LDS from the previous round).
      const float* f1 = out + ((size_t)b * Tg + (t0 - 1)) * (NXg * NYg);
      const float* f2 = f1 - NXg * NYg;
#pragma unroll
      for (int q = 0; q < CHUNK; ++q) {
        const int row = (q << 2) + w;
        if (row >= Kg && row < Kg + Rg) continue;  // core rows stay
        const int gr = wbase + row;
        float4 va = {0.f, 0.f, 0.f, 0.f};
        float4 vb = va;
        if (gr >= 0 && gr < NXg) {
          va = ld4g(f1 + gr * NYg + j4);
          vb = ld4g(f2 + gr * NYg + j4);
        }
        st4g(u1 + row * NYg + j4, va);
        st4g(u2 + row * NYg + j4, vb);
      }
      __syncthreads();
    }

    for (int s = 1; s <= Kg; ++s) {
      const int hi = NWg - s;        // valid new-frame rows: [s, hi)

      // Phase 1: batch-load u1 rows [start-1, start+CHUNK] and u2 rows
      // [start, start+CHUNK) that are inside the valid pyramid. Independent
      // ds_read_b128s -> compiler clusters them, one latency per step.
      float4 a[CHUNK + 2];
#pragma unroll
      for (int q = 0; q < CHUNK + 2; ++q) {
        const int row = start - 1 + q;
        if (row >= s - 1 && row <= hi)
          a[q] = ld4g(u1 + row * NYg + j4);
      }
      float4 v2[CHUNK];
#pragma unroll
      for (int q = 0; q < CHUNK; ++q) {
        const int row = start + q;
        if (row >= s && row < hi)
          v2[q] = ld4g(u2 + row * NYg + j4);
      }

      // Phase 2: compute + in-place write into u2 (single writer per row).
#pragma unroll
      for (int q = 0; q < CHUNK; ++q) {
        const int row = start + q;
        const int gr  = wbase + row;
        if (row >= s && row < hi && gr >= 0 && gr < NXg) {
          const float4 cU = a[q], cC = a[q + 1], cD = a[q + 2], vv = v2[q];
          float lfe = __shfl_up(cC.w, 1);   // col 4j-1 from lane j-1
          float rte = __shfl_down(cC.x, 1); // col 4j+4 from lane j+1
          if (j == 0)  lfe = 0.f;           // domain boundary col -1
          if (j == 63) rte = 0.f;           // domain boundary col 256
          float4 un;
          un.x = Pc[q].x * cC.x - Qc[q].x * vv.x +
                 Rc[q].x * ((cU.x + cD.x) + (lfe  + cC.y) - 4.f * cC.x);
          un.y = Pc[q].y * cC.y - Qc[q].y * vv.y +
                 Rc[q].y * ((cU.y + cD.y) + (cC.x + cC.z) - 4.f * cC.y);
          un.z = Pc[q].z * cC.z - Qc[q].z * vv.z +
                 Rc[q].z * ((cU.z + cD.z) + (cC.y + cC.w) - 4.f * cC.z);
          un.w = Pc[q].w * cC.w - Qc[q].w * vv.w +
                 Rc[q].w * ((cU.w + cD.w) + (cC.z + rte) - 4.f * cC.w);
          st4g(u2 + row * NYg + j4, un);
        }
      }

      { float* t_ = u1; u1 = u2; u2 = t_; }  // u1 now holds frame t

      // Point source (after update, matching reference .at[].add): the wave
      // owning row si adds it wherever the pyramid is valid.
      if (w == wsrc && j == jsrc && si >= s && si < hi)
        u1[si * NYg + sy] += xs[t0 + s - 1];

      __syncthreads();

      // Store core rows of frame t (wave w <-> core row w). Issued right
      // after the barrier so it retires during the next step's compute.
      {
        const int t = t0 + s - 1;
        const float4 core = ld4g(u1 + (Kg + w) * NYg + j4);
        st4g(out + ((size_t)b * Tg + t) * (NXg * NYg) + (r0 + w) * NYg + j4, core);
      }
    }
  }
}

extern "C" void kernel_launch(void* const* d_in, const int* in_sizes, int n_in,
                              void* d_out, int out_size, void* d_ws, size_t ws_size,
                              hipStream_t stream) {
  const float* x   = (const float*)d_in[0];
  const float* c2  = (const float*)d_in[1];
  const float* A1  = (const float*)d_in[2];
  const float* A3  = (const float*)d_in[3];
  const float* A2  = (const float*)d_in[4];
  const float* ih2 = (const float*)d_in[5];
  const int*   sx  = (const int*)d_in[6];
  const int*   sy  = (const int*)d_in[7];
  float* out = (float*)d_out;
  unsigned* bar = (unsigned*)d_ws;

  // Barrier counters (4 batches x 32 u32) must be zero at kernel start.
  hipMemsetAsync(d_ws, 0, 512, stream);

  void* args[] = {(void*)&x, (void*)&c2, (void*)&A1, (void*)&A3, (void*)&A2,
                  (void*)&ih2, (void*)&sx, (void*)&sy, (void*)&out, (void*)&bar};
  hipError_t e = hipLaunchCooperativeKernel(
      (const void*)WaveCell_14894946582958_kernel, dim3(NBLK), dim3(256), args,
      0, stream);
  if (e != hipSuccess) {
    // Fallback: plain launch. 256 blocks (<=50KB LDS, 1+/CU) are co-resident
    // on 256 CUs; per-batch barrier semantics identical.
    WaveCell_14894946582958_kernel<<<dim3(NBLK), dim3(256), 0, stream>>>(
        x, c2, A1, A3, A2, ih2, sx, sy, out, bar);
  }
}

// Round 4
// 957.700 us; speedup vs baseline: 1.3635x; 1.3635x over previous
//
#include <hip/hip_runtime.h>

// WaveCell: 2D wave equation, B=4, T=300, 256x256, PML coeffs.
// Persistent cooperative kernel; row-stripe temporal blocking.
//   256 blocks = 4 batches x 64 stripes (R=4 core rows); 256 threads/block.
//   Wave w=tid>>6 owns window rows [1+7w, 1+7w+7); lane j owns cols [4j,4j+4).
//   K=13 steps per grid barrier; LDS window NW=30 rows x 2 frames (60KB static).
//   Coefficients (P=A1*A2, Q=A1*A3, R=A1*c2/h^2) in registers; inner 13-step
//   loop fully unrolled (static reg indices, immediate LDS offsets).
//   Core rows stored to global FROM REGISTERS in the compute loop (no
//   read-after-barrier race); source folded into the register before store.
//   Barrier: relaxed-poll + single acquire fence; release via fetch_add.
//   XCD remap: batch = XCD pair, so halo traffic is same-L2 except one seam.

#define NXg 256
#define NYg 256
#define Bg  4
#define Tg  300
#define Kg  13
#define Rg  4
#define NWg (Rg + 2 * Kg)      // 30
#define STRIPES (NXg / Rg)     // 64
#define NBLK (Bg * STRIPES)    // 256
#define GRP STRIPES
#define CHUNK ((NWg - 2) / 4)  // 7 rows per wave, rows [1,29) covered exactly
#define NROUND ((Tg + Kg - 1) / Kg)  // 24
#define GRID (NXg * NYg)

static_assert(CHUNK * 4 == NWg - 2, "waves must tile updated rows exactly");

__device__ __forceinline__ float4 ld4(const float* p) {
  return *reinterpret_cast<const float4*>(p);
}
__device__ __forceinline__ void st4(float* p, float4 v) {
  *reinterpret_cast<float4*>(p) = v;
}

__device__ __forceinline__ void batch_barrier(unsigned* cnt, unsigned* gen) {
  __syncthreads();  // drains every wave's vmcnt/lgkmcnt before leader arrives
  if (threadIdx.x == 0) {
    unsigned g = __hip_atomic_load(gen, __ATOMIC_RELAXED, __HIP_MEMORY_SCOPE_AGENT);
    unsigned a = __hip_atomic_fetch_add(cnt, 1u, __ATOMIC_RELEASE, __HIP_MEMORY_SCOPE_AGENT);
    if (a == GRP - 1u) {
      __hip_atomic_store(cnt, 0u, __ATOMIC_RELAXED, __HIP_MEMORY_SCOPE_AGENT);
      __hip_atomic_store(gen, g + 1u, __ATOMIC_RELEASE, __HIP_MEMORY_SCOPE_AGENT);
    } else {
      while (__hip_atomic_load(gen, __ATOMIC_RELAXED, __HIP_MEMORY_SCOPE_AGENT) == g)
        __builtin_amdgcn_s_sleep(2);
    }
    __builtin_amdgcn_fence(__ATOMIC_ACQUIRE, "agent");  // one inv, not per-poll
  }
  __syncthreads();
}

__global__ __launch_bounds__(256, 1)
void WaveCell_14894946582958_kernel(const float* __restrict__ x,
                                    const float* __restrict__ c2,
                                    const float* __restrict__ A1,
                                    const float* __restrict__ A3,
                                    const float* __restrict__ A2p,
                                    const float* __restrict__ ih2p,
                                    const int*   __restrict__ sxp,
                                    const int*   __restrict__ syp,
                                    float* __restrict__ out,
                                    unsigned* __restrict__ bar) {
  __shared__ __align__(16) float Ua[NWg * NYg];  // 30 KB
  __shared__ __align__(16) float Ub[NWg * NYg];  // 30 KB

  const int tid = threadIdx.x;
  const int w   = __builtin_amdgcn_readfirstlane(tid >> 6);  // wave 0..3
  const int j   = tid & 63;
  const int j4  = j << 2;
  const int bid = blockIdx.x;
  // XCD remap: XCD = bid%8 (dispatch round-robin). Batch b on XCD pair
  // {2b,2b+1}; stripes 0-31 on the even XCD, 32-63 on the odd one.
  const int b      = (bid >> 1) & 3;
  const int stripe = ((bid & 1) << 5) | (bid >> 3);
  const int r0     = stripe << 2;
  const int wbase  = r0 - Kg;        // global row of window row 0

  const float A2v = A2p[0];
  const float ih2 = ih2p[0];
  const int sx = sxp[0], sy = syp[0];

  // Coefficients for my 7 rows, in registers.
  const int start = 1 + w * CHUNK;   // 1, 8, 15, 22
  float4 Pc[CHUNK], Qc[CHUNK], Rc[CHUNK];
#pragma unroll
  for (int q = 0; q < CHUNK; ++q) {
    const int gr = wbase + start + q;
    float4 a1 = {0.f, 0.f, 0.f, 0.f}, a3 = a1, cc = a1;
    if (gr >= 0 && gr < NXg) {
      a1 = ld4(A1 + gr * NYg + j4);
      a3 = ld4(A3 + gr * NYg + j4);
      cc = ld4(c2 + gr * NYg + j4);
    }
    Pc[q].x = a1.x * A2v; Pc[q].y = a1.y * A2v; Pc[q].z = a1.z * A2v; Pc[q].w = a1.w * A2v;
    Qc[q].x = a1.x * a3.x; Qc[q].y = a1.y * a3.y; Qc[q].z = a1.z * a3.z; Qc[q].w = a1.w * a3.w;
    Rc[q].x = a1.x * cc.x * ih2; Rc[q].y = a1.y * cc.y * ih2;
    Rc[q].z = a1.z * cc.z * ih2; Rc[q].w = a1.w * cc.w * ih2;
  }

  float* u1 = Ua;  // frame t-1
  float* u2 = Ub;  // frame t-2 (overwritten in place with frame t)
  unsigned* cnt = bar + (b << 6);    // 256B apart per batch
  unsigned* gen = cnt + 32;          // 128B from cnt: poll line != RMW line

  const int si   = sx - wbase;       // source row in window coords (uniform)
  const int jsrc = sy >> 2;
  const int esel = sy & 3;

  for (int r = 0; r < NROUND; ++r) {
    const int t0 = r * Kg;

    if (r == 0) {
      const float4 z = {0.f, 0.f, 0.f, 0.f};
#pragma unroll
      for (int q = 0; q < 8; ++q) {
        const int row = (q << 2) + w;
        if (row < NWg) { st4(u1 + row * NYg + j4, z); st4(u2 + row * NYg + j4, z); }
      }
    } else {
      batch_barrier(cnt, gen);
      // Halo reload: frames t0-1 -> u1, t0-2 -> u2 (core rows stay in LDS).
      const float* f1 = out + ((size_t)b * Tg + (t0 - 1)) * GRID;
      const float* f2 = f1 - GRID;
#pragma unroll
      for (int q = 0; q < 8; ++q) {
        const int row = (q << 2) + w;
        if (row < NWg && !(row >= Kg && row < Kg + Rg)) {
          const int gr = wbase + row;
          float4 va = {0.f, 0.f, 0.f, 0.f}, vb = va;
          if (gr >= 0 && gr < NXg) {
            va = ld4(f1 + gr * NYg + j4);
            vb = ld4(f2 + gr * NYg + j4);
          }
          st4(u1 + row * NYg + j4, va);
          st4(u2 + row * NYg + j4, vb);
        }
      }
    }

    // Source series for this round (uniform broadcast load, all threads).
    float xsrc[Kg];
#pragma unroll
    for (int q = 0; q < Kg; ++q)
      xsrc[q] = (t0 + q < Tg) ? x[b * Tg + t0 + q] : 0.f;

    __syncthreads();

#pragma unroll
    for (int s = 1; s <= Kg; ++s) {
      const int t = t0 + s - 1;
      if (t < Tg) {                      // uniform; skips tail of last round
        const int hi = NWg - s;          // compile-time after unroll

        // Phase 1: batch-load u1 rows [start-1, start+CHUNK], u2 own rows.
        float4 a[CHUNK + 2];
#pragma unroll
        for (int q = 0; q < CHUNK + 2; ++q) {
          const int row = start - 1 + q;
          if (row >= s - 1 && row <= hi) a[q] = ld4(u1 + row * NYg + j4);
        }
        float4 v2[CHUNK];
#pragma unroll
        for (int q = 0; q < CHUNK; ++q) {
          const int row = start + q;
          if (row >= s && row < hi) v2[q] = ld4(u2 + row * NYg + j4);
        }

        // Phase 2: compute; write u2 in place; core rows go straight to out.
#pragma unroll
        for (int q = 0; q < CHUNK; ++q) {
          const int row = start + q;
          const int gr  = wbase + row;
          if (row >= s && row < hi && gr >= 0 && gr < NXg) {
            const float4 cU = a[q], cC = a[q + 1], cD = a[q + 2], vv = v2[q];
            float lfe = __shfl_up(cC.w, 1);
            float rte = __shfl_down(cC.x, 1);
            if (j == 0)  lfe = 0.f;
            if (j == 63) rte = 0.f;
            float4 un;
            un.x = Pc[q].x * cC.x - Qc[q].x * vv.x +
                   Rc[q].x * ((cU.x + cD.x) + (lfe  + cC.y) - 4.f * cC.x);
            un.y = Pc[q].y * cC.y - Qc[q].y * vv.y +
                   Rc[q].y * ((cU.y + cD.y) + (cC.x + cC.z) - 4.f * cC.y);
            un.z = Pc[q].z * cC.z - Qc[q].z * vv.z +
                   Rc[q].z * ((cU.z + cD.z) + (cC.y + cC.w) - 4.f * cC.z);
            un.w = Pc[q].w * cC.w - Qc[q].w * vv.w +
                   Rc[q].w * ((cU.w + cD.w) + (cC.z + rte) - 4.f * cC.w);
            // Source folded in BEFORE the LDS write and the core store.
            if (row == si && si >= s && si < hi && j == jsrc) {
              const float xv = xsrc[s - 1];
              un.x += (esel == 0) ? xv : 0.f;
              un.y += (esel == 1) ? xv : 0.f;
              un.z += (esel == 2) ? xv : 0.f;
              un.w += (esel == 3) ? xv : 0.f;
            }
            st4(u2 + row * NYg + j4, un);
            // Core rows: store from registers (race-free, no extra LDS read).
            if (row >= Kg && row < Kg + Rg) {
              st4(out + ((size_t)b * Tg + t) * GRID + gr * NYg + j4, un);
            }
          }
        }
        { float* tmp = u1; u1 = u2; u2 = tmp; }  // u1 now holds frame t
        __syncthreads();  // neighbors' boundary rows ready for next step
      }
    }
  }
}

extern "C" void kernel_launch(void* const* d_in, const int* in_sizes, int n_in,
                              void* d_out, int out_size, void* d_ws, size_t ws_size,
                              hipStream_t stream) {
  const float* x   = (const float*)d_in[0];
  const float* c2  = (const float*)d_in[1];
  const float* A1  = (const float*)d_in[2];
  const float* A3  = (const float*)d_in[3];
  const float* A2  = (const float*)d_in[4];
  const float* ih2 = (const float*)d_in[5];
  const int*   sx  = (const int*)d_in[6];
  const int*   sy  = (const int*)d_in[7];
  float* out = (float*)d_out;
  unsigned* bar = (unsigned*)d_ws;

  // Barrier state (4 batches x 256B) must be zero at kernel start each replay.
  hipMemsetAsync(d_ws, 0, 1024, stream);

  void* args[] = {(void*)&x, (void*)&c2, (void*)&A1, (void*)&A3, (void*)&A2,
                  (void*)&ih2, (void*)&sx, (void*)&sy, (void*)&out, (void*)&bar};
  hipError_t e = hipLaunchCooperativeKernel(
      (const void*)WaveCell_14894946582958_kernel, dim3(NBLK), dim3(256), args,
      0, stream);
  if (e != hipSuccess) {
    WaveCell_14894946582958_kernel<<<dim3(NBLK), dim3(256), 0, stream>>>(
        x, c2, A1, A3, A2, ih2, sx, sy, out, bar);
  }
}

// Round 7
// 742.531 us; speedup vs baseline: 1.7587x; 1.2898x over previous
//
#include <hip/hip_runtime.h>

// WaveCell: 2D wave equation, B=4, T=300, 256x256, PML coeffs.
// Persistent-style kernel; row-stripe temporal blocking; NO global barrier:
// point-to-point neighbor-flag sync (each block depends only on stripe+-4).
//   256 blocks = 4 batches x 64 stripes (R=4 core rows); 512 threads/block
//   (8 waves -> 2 waves/SIMD for latency hiding).
//   Wave w owns window rows [1+4w, 1+4w+4); lane j owns cols [4j,4j+4).
//   K=15 steps/round, 20 rounds; LDS window NW=34 rows x 2 frames = 68KB
//   (dynamic; >64KB is fine on gfx950 with the attribute set).
//   Coefficients (P=A1*A2, Q=A1*A3, R=A1*c2/h^2) in registers; 15-step inner
//   loop fully unrolled; core rows stored to global from registers.
//   Sync: after round r each block release-stores flag=r+1; before round r+1
//   wave 0 polls its <=8 neighbor flags (lanes 0-7, relaxed) then one acquire
//   fence. Removes 64-block straggler coupling; blocks pipeline locally.
//   Co-residency: 256 blocks on 256 CUs; worst-case 2 blocks/CU still fits
//   (136KB LDS, 16 waves), so all blocks are resident -> no deadlock.
//   XCD remap: batch = XCD pair; halo traffic stays on-XCD except one seam.

#define NXg 256
#define NYg 256
#define Bg  4
#define Tg  300
#define Kg  15
#define Rg  4
#define NWg (Rg + 2 * Kg)        // 34
#define STRIPES (NXg / Rg)       // 64
#define NBLK (Bg * STRIPES)      // 256
#define NTHR 512
#define NWAVE (NTHR / 64)        // 8
#define CHUNK ((NWg - 2) / NWAVE)  // 4 rows per wave, rows [1,33) exactly
#define NROUND (Tg / Kg)         // 20
#define GRID (NXg * NYg)

static_assert(CHUNK * NWAVE == NWg - 2, "waves must tile updated rows exactly");
static_assert(NROUND * Kg == Tg, "rounds must tile T exactly");

__device__ __forceinline__ float4 ld4(const float* p) {
  return *reinterpret_cast<const float4*>(p);
}
__device__ __forceinline__ void st4(float* p, float4 v) {
  *reinterpret_cast<float4*>(p) = v;
}

__global__ __launch_bounds__(NTHR, 1)
void WaveCell_14894946582958_kernel(const float* __restrict__ x,
                                    const float* __restrict__ c2,
                                    const float* __restrict__ A1,
                                    const float* __restrict__ A3,
                                    const float* __restrict__ A2p,
                                    const float* __restrict__ ih2p,
                                    const int*   __restrict__ sxp,
                                    const int*   __restrict__ syp,
                                    float* __restrict__ out,
                                    unsigned* __restrict__ bar) {
  extern __shared__ __align__(16) float lds[];
  float* Ua = lds;               // [NWg][NYg] frame buffer A (34 KB)
  float* Ub = lds + NWg * NYg;   // [NWg][NYg] frame buffer B (34 KB)

  const int tid = threadIdx.x;
  const int w   = __builtin_amdgcn_readfirstlane(tid >> 6);  // wave 0..7
  const int j   = tid & 63;
  const int j4  = j << 2;
  const int bid = blockIdx.x;
  // XCD remap: XCD = bid%8 (dispatch round-robin). Batch b on XCD pair
  // {2b,2b+1}; stripes 0-31 on the even XCD, 32-63 on the odd one.
  const int b      = (bid >> 1) & 3;
  const int stripe = ((bid & 1) << 5) | (bid >> 3);
  const int r0     = stripe << 2;
  const int wbase  = r0 - Kg;          // global row of window row 0

  const float A2v = A2p[0];
  const float ih2 = ih2p[0];
  const int sx = sxp[0], sy = syp[0];

  // Coefficients for my CHUNK rows, in registers.
  const int start = 1 + w * CHUNK;     // 1,5,9,...,29
  float4 Pc[CHUNK], Qc[CHUNK], Rc[CHUNK];
#pragma unroll
  for (int q = 0; q < CHUNK; ++q) {
    const int gr = wbase + start + q;
    float4 a1 = {0.f, 0.f, 0.f, 0.f}, a3 = a1, cc = a1;
    if (gr >= 0 && gr < NXg) {
      a1 = ld4(A1 + gr * NYg + j4);
      a3 = ld4(A3 + gr * NYg + j4);
      cc = ld4(c2 + gr * NYg + j4);
    }
    Pc[q].x = a1.x * A2v; Pc[q].y = a1.y * A2v; Pc[q].z = a1.z * A2v; Pc[q].w = a1.w * A2v;
    Qc[q].x = a1.x * a3.x; Qc[q].y = a1.y * a3.y; Qc[q].z = a1.z * a3.z; Qc[q].w = a1.w * a3.w;
    Rc[q].x = a1.x * cc.x * ih2; Rc[q].y = a1.y * cc.y * ih2;
    Rc[q].z = a1.z * cc.z * ih2; Rc[q].w = a1.w * cc.w * ih2;
  }

  float* u1 = Ua;  // frame t-1
  float* u2 = Ub;  // frame t-2 (overwritten in place with frame t)

  // Flags: one u32 per (batch,stripe), 64B apart. flag = #completed rounds.
  unsigned* myflag = bar + ((unsigned)((b << 6) | stripe) << 4);
  // Wave-0 lanes 0..7 poll neighbor stripes -4..-1,+1..+4.
  const int noff    = (j < 4) ? (j - 4) : (j - 3);
  const int nstripe = stripe + noff;
  const bool need   = (j < 8) && nstripe >= 0 && nstripe < STRIPES;
  unsigned* nflag = bar + ((unsigned)((b << 6) | (nstripe & 63)) << 4);

  const int si   = sx - wbase;         // source row in window coords (uniform)
  const int jsrc = sy >> 2;
  const int esel = sy & 3;

  for (int r = 0; r < NROUND; ++r) {
    const int t0 = r * Kg;

    if (r == 0) {
      const float4 z = {0.f, 0.f, 0.f, 0.f};
#pragma unroll
      for (int q = 0; q < 5; ++q) {
        const int row = q * NWAVE + w;
        if (row < NWg) { st4(u1 + row * NYg + j4, z); st4(u2 + row * NYg + j4, z); }
      }
    } else {
      // Wait for the <=8 neighbors whose core rows overlap my halo.
      if (w == 0) {
        while (!__all(!need ||
               (__hip_atomic_load(nflag, __ATOMIC_RELAXED, __HIP_MEMORY_SCOPE_AGENT)
                >= (unsigned)r)))
          __builtin_amdgcn_s_sleep(1);
        __builtin_amdgcn_fence(__ATOMIC_ACQUIRE, "agent");
      }
      __syncthreads();
      // Halo reload: frames t0-1 -> u1, t0-2 -> u2 (core rows stay in LDS).
      const float* f1 = out + ((size_t)b * Tg + (t0 - 1)) * GRID;
      const float* f2 = f1 - GRID;
#pragma unroll
      for (int q = 0; q < 5; ++q) {
        const int row = q * NWAVE + w;
        if (row < NWg && !(row >= Kg && row < Kg + Rg)) {
          const int gr = wbase + row;
          float4 va = {0.f, 0.f, 0.f, 0.f}, vb = va;
          if (gr >= 0 && gr < NXg) {
            va = ld4(f1 + gr * NYg + j4);
            vb = ld4(f2 + gr * NYg + j4);
          }
          st4(u1 + row * NYg + j4, va);
          st4(u2 + row * NYg + j4, vb);
        }
      }
    }

    // Source series for this round (uniform broadcast load).
    float xsrc[Kg];
#pragma unroll
    for (int q = 0; q < Kg; ++q) xsrc[q] = x[b * Tg + t0 + q];

    __syncthreads();

#pragma unroll
    for (int s = 1; s <= Kg; ++s) {
      const int t  = t0 + s - 1;
      const int hi = NWg - s;          // compile-time after unroll

      // Phase 1: batch-load u1 rows [start-1, start+CHUNK], u2 own rows.
      float4 a[CHUNK + 2];
#pragma unroll
      for (int q = 0; q < CHUNK + 2; ++q) {
        const int row = start - 1 + q;
        if (row >= s - 1 && row <= hi) a[q] = ld4(u1 + row * NYg + j4);
      }
      float4 v2[CHUNK];
#pragma unroll
      for (int q = 0; q < CHUNK; ++q) {
        const int row = start + q;
        if (row >= s && row < hi) v2[q] = ld4(u2 + row * NYg + j4);
      }

      // Phase 2: compute; write u2 in place; core rows go straight to out.
#pragma unroll
      for (int q = 0; q < CHUNK; ++q) {
        const int row = start + q;
        const int gr  = wbase + row;
        if (row >= s && row < hi && gr >= 0 && gr < NXg) {
          const float4 cU = a[q], cC = a[q + 1], cD = a[q + 2], vv = v2[q];
          float lfe = __shfl_up(cC.w, 1);
          float rte = __shfl_down(cC.x, 1);
          if (j == 0)  lfe = 0.f;
          if (j == 63) rte = 0.f;
          float4 un;
          un.x = Pc[q].x * cC.x - Qc[q].x * vv.x +
                 Rc[q].x * ((cU.x + cD.x) + (lfe  + cC.y) - 4.f * cC.x);
          un.y = Pc[q].y * cC.y - Qc[q].y * vv.y +
                 Rc[q].y * ((cU.y + cD.y) + (cC.x + cC.z) - 4.f * cC.y);
          un.z = Pc[q].z * cC.z - Qc[q].z * vv.z +
                 Rc[q].z * ((cU.z + cD.z) + (cC.y + cC.w) - 4.f * cC.z);
          un.w = Pc[q].w * cC.w - Qc[q].w * vv.w +
                 Rc[q].w * ((cU.w + cD.w) + (cC.z + rte) - 4.f * cC.w);
          // Source folded in BEFORE the LDS write and the core store.
          if (row == si && si >= s && si < hi && j == jsrc) {
            const float xv = xsrc[s - 1];
            un.x += (esel == 0) ? xv : 0.f;
            un.y += (esel == 1) ? xv : 0.f;
            un.z += (esel == 2) ? xv : 0.f;
            un.w += (esel == 3) ? xv : 0.f;
          }
          st4(u2 + row * NYg + j4, un);
          // Core rows: store from registers (race-free, no extra LDS read).
          if (row >= Kg && row < Kg + Rg) {
            st4(out + ((size_t)b * Tg + t) * GRID + gr * NYg + j4, un);
          }
        }
      }
      { float* tmp = u1; u1 = u2; u2 = tmp; }  // u1 now holds frame t
      __syncthreads();  // neighbors' boundary rows ready for next step
    }

    // Publish round completion (all waves' stores drained at the barrier
    // above; release store writes back L2 before the flag becomes visible).
    if (tid == 0 && r + 1 < NROUND) {
      __hip_atomic_store(myflag, (unsigned)(r + 1),
                         __ATOMIC_RELEASE, __HIP_MEMORY_SCOPE_AGENT);
    }
  }
}

extern "C" void kernel_launch(void* const* d_in, const int* in_sizes, int n_in,
                              void* d_out, int out_size, void* d_ws, size_t ws_size,
                              hipStream_t stream) {
  const float* x   = (const float*)d_in[0];
  const float* c2  = (const float*)d_in[1];
  const float* A1  = (const float*)d_in[2];
  const float* A3  = (const float*)d_in[3];
  const float* A2  = (const float*)d_in[4];
  const float* ih2 = (const float*)d_in[5];
  const int*   sx  = (const int*)d_in[6];
  const int*   sy  = (const int*)d_in[7];
  float* out = (float*)d_out;
  unsigned* bar = (unsigned*)d_ws;

  // Neighbor flags (256 x 64B) must be zero at kernel start on every replay.
  hipMemsetAsync(d_ws, 0, 256 * 64, stream);

  // Host-side, not stream-captured; done unconditionally every call (no
  // static guards per harness rules).
  const int ldsBytes = 2 * NWg * NYg * (int)sizeof(float);  // 69632 B
  hipFuncSetAttribute((const void*)WaveCell_14894946582958_kernel,
                      hipFuncAttributeMaxDynamicSharedMemorySize, ldsBytes);

  WaveCell_14894946582958_kernel<<<dim3(NBLK), dim3(NTHR), ldsBytes, stream>>>(
      x, c2, A1, A3, A2, ih2, sx, sy, out, bar);
}